// Round 1
// 208.578 us; speedup vs baseline: 1.1247x; 1.1247x over previous
//
#include <hip/hip_runtime.h>

// L=4096, N=B=64. CH=8 -> CN=512 chunks (2 WG/CU on 256 CUs).
// Scan hierarchy: 512 chunks = 64 groups x 8 = 8 supers x 8 groups x 8.
#define TL 4096
#define NB 64
#define CH 8
#define CN 512
#define AS 72          // LDS row stride (bf16 elems): 144 B = 9 x 16B groups (odd -> conflict-free b128)

typedef __attribute__((ext_vector_type(8))) short short8;   // 8 x bf16 MFMA frag
typedef __attribute__((ext_vector_type(4))) short short4v;  // 4 x bf16 (b64 store)
typedef __attribute__((ext_vector_type(4))) float floatx4;  // MFMA acc

__device__ inline floatx4 mfma_bf16(short8 a, short8 b, floatx4 c) {
    return __builtin_amdgcn_mfma_f32_16x16x32_bf16(a, b, c, 0, 0, 0);
}

// fp32 -> (hi, lo) bf16 pair, RNE both. x ~= hi + lo to ~2^-17 rel.
__device__ inline void split_bf16(float x, short& h, short& l) {
    union { float f; unsigned u; } v; v.f = x;
    unsigned uh = v.u + 0x7FFFu + ((v.u >> 16) & 1u);
    h = (short)(uh >> 16);
    union { unsigned u; float f; } hv; hv.u = ((unsigned)(unsigned short)h) << 16;
    float r = x - hv.f;
    union { float f; unsigned u; } rv; rv.f = r;
    unsigned ul = rv.u + 0x7FFFu + ((rv.u >> 16) & 1u);
    l = (short)(ul >> 16);
}

// ---------------------------------------------------------------------------
// Phase 1 (forward): per chunk c, S <- A[t]*S (S0=I), V <- A[t]*V + b_t (x) i_t.
// Emits PT[c] = S^T, VT[c] = V^T (fp32, row-major in the transposed index).
// ---------------------------------------------------------------------------
__global__ __launch_bounds__(256, 2)
void hippo_phase1(const float* __restrict__ inp, const float* __restrict__ Ag,
                  const float* __restrict__ Bst,
                  float* __restrict__ PT, float* __restrict__ VT)
{
    __shared__ short Ah[NB][AS], Al[NB][AS];
    __shared__ short SBh[NB][AS], SBl[NB][AS];
    __shared__ short VBh[NB][AS], VBl[NB][AS];
    __shared__ float btl[NB], itl[NB];

    const int tid  = threadIdx.x;
    const int c    = blockIdx.x;
    const int t0   = c * CH;
    const int w    = tid >> 6, lane = tid & 63;
    const int quad = lane >> 4, l15 = lane & 15;

    // SB = I (bf16(1.0) = 0x3F80), VB = 0
#pragma unroll
    for (int q = 0; q < 16; ++q) {
        int f = tid + q * 256;
        int n = f >> 6, k = f & 63;
        SBh[n][k] = (n == k) ? (short)0x3F80 : (short)0;
        SBl[n][k] = 0; VBh[n][k] = 0; VBl[n][k] = 0;
    }

    float4 pre[4];
    {
        const float4* Ap = (const float4*)(Ag + (size_t)t0 * 4096);
#pragma unroll
        for (int q = 0; q < 4; ++q) pre[q] = Ap[tid + q * 256];
    }

    floatx4 accS[4], accV[4];

    for (int s = 0; s < CH; ++s) {
        int t = t0 + s;
#pragma unroll
        for (int q = 0; q < 4; ++q) {
            int f = tid + q * 256;
            int m = f >> 4, k0 = (f & 15) * 4;
            float vv[4] = {pre[q].x, pre[q].y, pre[q].z, pre[q].w};
            short4v h4, l4;
#pragma unroll
            for (int r = 0; r < 4; ++r) { short hh, ll; split_bf16(vv[r], hh, ll); h4[r]=hh; l4[r]=ll; }
            *(short4v*)&Ah[m][k0] = h4;
            *(short4v*)&Al[m][k0] = l4;
        }
        if (tid < 64) { btl[tid] = Bst[(size_t)t*64 + tid]; itl[tid] = inp[(size_t)t*64 + tid]; }
        if (s + 1 < CH) {
            const float4* Ap = (const float4*)(Ag + (size_t)(t+1) * 4096);
#pragma unroll
            for (int q = 0; q < 4; ++q) pre[q] = Ap[tid + q * 256];
        }
        __syncthreads();   // A, btl/itl, prev SB/VB visible

#pragma unroll
        for (int ni = 0; ni < 4; ++ni) {
            float ib = itl[16*ni + l15];
#pragma unroll
            for (int r = 0; r < 4; ++r) {
                accS[ni][r] = 0.0f;
                accV[ni][r] = btl[16*w + 4*quad + r] * ib;   // u_t = b_t (x) i_t in C-layout
            }
        }
#pragma unroll
        for (int kc = 0; kc < 2; ++kc) {
            int ko = 32*kc + 8*quad;
            short8 aH = *(const short8*)&Ah[16*w + l15][ko];
            short8 aL = *(const short8*)&Al[16*w + l15][ko];
#pragma unroll
            for (int ni = 0; ni < 4; ++ni) {
                int n = 16*ni + l15;
                short8 sH = *(const short8*)&SBh[n][ko];
                short8 sL = *(const short8*)&SBl[n][ko];
                accS[ni] = mfma_bf16(aH, sH, accS[ni]);
                accS[ni] = mfma_bf16(aH, sL, accS[ni]);
                accS[ni] = mfma_bf16(aL, sH, accS[ni]);
                short8 vH = *(const short8*)&VBh[n][ko];
                short8 vL = *(const short8*)&VBl[n][ko];
                accV[ni] = mfma_bf16(aH, vH, accV[ni]);
                accV[ni] = mfma_bf16(aH, vL, accV[ni]);
                accV[ni] = mfma_bf16(aL, vH, accV[ni]);
            }
        }
        __syncthreads();   // all SB/VB reads done

        if (s + 1 < CH) {
#pragma unroll
            for (int ni = 0; ni < 4; ++ni) {
                int cc = 16*ni + l15, r0 = 16*w + 4*quad;
                short4v h4, l4;
#pragma unroll
                for (int r = 0; r < 4; ++r) { short hh,ll; split_bf16(accS[ni][r],hh,ll); h4[r]=hh; l4[r]=ll; }
                *(short4v*)&SBh[cc][r0] = h4; *(short4v*)&SBl[cc][r0] = l4;
#pragma unroll
                for (int r = 0; r < 4; ++r) { short hh,ll; split_bf16(accV[ni][r],hh,ll); h4[r]=hh; l4[r]=ll; }
                *(short4v*)&VBh[cc][r0] = h4; *(short4v*)&VBl[cc][r0] = l4;
            }
        }
    }
#pragma unroll
    for (int ni = 0; ni < 4; ++ni) {
        int cc = 16*ni + l15, r0 = 16*w + 4*quad;
        *(floatx4*)(PT + (size_t)c*4096 + cc*64 + r0) = accS[ni];
        *(floatx4*)(VT + (size_t)c*4096 + cc*64 + r0) = accV[ni];
    }
}

// ---------------------------------------------------------------------------
// Sequential in-place scan of 8 elements per block.
// Elements at chunk idx = blockIdx.x*bstride + off0 + i*estride, i=0..7.
// Each slot i is overwritten with the inclusive prefix over elements 0..i.
// acc holds prefix (earlier); element i is later: Pnew = P_i*Pacc (Aop = P_i),
// Vnew = P_i*Vacc + V_i.  Reuses phase1's inner structure.
// ---------------------------------------------------------------------------
__global__ __launch_bounds__(256, 2)
void hippo_seqscan(float* __restrict__ PT, float* __restrict__ VT,
                   int bstride, int off0, int estride)
{
    __shared__ short PAh[NB][AS], PAl[NB][AS];   // P_i row-major (Aop)
    __shared__ short PBh[NB][AS], PBl[NB][AS];   // Pacc^T (Bop)
    __shared__ short VBh[NB][AS], VBl[NB][AS];   // Vacc^T (Bop)

    const int tid  = threadIdx.x;
    const int base = blockIdx.x * bstride + off0;
    const int w    = tid >> 6, lane = tid & 63;
    const int quad = lane >> 4, l15 = lane & 15;

    // element 0 -> Bop LDS (direct row copy + split); its slot stays as-is.
    {
        const float* p0 = PT + (size_t)base * 4096;
        const float* v0 = VT + (size_t)base * 4096;
#pragma unroll
        for (int q = 0; q < 4; ++q) {
            int f = tid + q * 256;
            int n = f >> 4, k0 = (f & 15) * 4;
            float4 pp = *(const float4*)(p0 + n * 64 + k0);
            float4 vv = *(const float4*)(v0 + n * 64 + k0);
            float pa[4] = {pp.x, pp.y, pp.z, pp.w};
            float va[4] = {vv.x, vv.y, vv.z, vv.w};
            short4v ph4, pl4, vh4, vl4;
#pragma unroll
            for (int r = 0; r < 4; ++r) {
                short hh, ll;
                split_bf16(pa[r], hh, ll); ph4[r] = hh; pl4[r] = ll;
                split_bf16(va[r], hh, ll); vh4[r] = hh; vl4[r] = ll;
            }
            *(short4v*)&PBh[n][k0] = ph4; *(short4v*)&PBl[n][k0] = pl4;
            *(short4v*)&VBh[n][k0] = vh4; *(short4v*)&VBl[n][k0] = vl4;
        }
    }

    // prefetch element 1 (Aop transpose pattern + C-layout V)
    float4 preA[4], preV[4];
    {
        const float* pc = PT + (size_t)(base + estride) * 4096;
        const float* vc = VT + (size_t)(base + estride) * 4096;
#pragma unroll
        for (int q = 0; q < 4; ++q) {
            int f = tid + q * 256;
            int k = f & 63, m0 = (f >> 6) * 4;
            preA[q] = *(const float4*)(pc + k * 64 + m0);
        }
#pragma unroll
        for (int ni = 0; ni < 4; ++ni) {
            int cc = 16 * ni + l15, r0 = 16 * w + 4 * quad;
            preV[ni] = *(const float4*)(vc + cc * 64 + r0);
        }
    }

    for (int i = 1; i < 8; ++i) {
        // stage Aop = P_i from prefetch (transpose: PT[k][m] -> PA[m][k])
#pragma unroll
        for (int q = 0; q < 4; ++q) {
            int f = tid + q * 256;
            int k = f & 63, m0 = (f >> 6) * 4;
            float vv[4] = {preA[q].x, preA[q].y, preA[q].z, preA[q].w};
#pragma unroll
            for (int r = 0; r < 4; ++r) {
                short hh, ll; split_bf16(vv[r], hh, ll);
                PAh[m0 + r][k] = hh; PAl[m0 + r][k] = ll;
            }
        }
        floatx4 accP[4], accV[4];
#pragma unroll
        for (int ni = 0; ni < 4; ++ni) {
            accV[ni][0] = preV[ni].x; accV[ni][1] = preV[ni].y;
            accV[ni][2] = preV[ni].z; accV[ni][3] = preV[ni].w;
            accP[ni][0] = accP[ni][1] = accP[ni][2] = accP[ni][3] = 0.0f;
        }
        if (i + 1 < 8) {   // prefetch next element
            const float* pc = PT + (size_t)(base + (i + 1) * estride) * 4096;
            const float* vc = VT + (size_t)(base + (i + 1) * estride) * 4096;
#pragma unroll
            for (int q = 0; q < 4; ++q) {
                int f = tid + q * 256;
                int k = f & 63, m0 = (f >> 6) * 4;
                preA[q] = *(const float4*)(pc + k * 64 + m0);
            }
#pragma unroll
            for (int ni = 0; ni < 4; ++ni) {
                int cc = 16 * ni + l15, r0 = 16 * w + 4 * quad;
                preV[ni] = *(const float4*)(vc + cc * 64 + r0);
            }
        }
        __syncthreads();   // PA + (PB/VB from prev iter) visible

#pragma unroll
        for (int kc = 0; kc < 2; ++kc) {
            int ko = 32 * kc + 8 * quad;
            short8 aH = *(const short8*)&PAh[16 * w + l15][ko];
            short8 aL = *(const short8*)&PAl[16 * w + l15][ko];
#pragma unroll
            for (int ni = 0; ni < 4; ++ni) {
                int n = 16 * ni + l15;
                short8 pH = *(const short8*)&PBh[n][ko];
                short8 pL = *(const short8*)&PBl[n][ko];
                accP[ni] = mfma_bf16(aH, pH, accP[ni]);
                accP[ni] = mfma_bf16(aH, pL, accP[ni]);
                accP[ni] = mfma_bf16(aL, pH, accP[ni]);
                short8 vH = *(const short8*)&VBh[n][ko];
                short8 vL = *(const short8*)&VBl[n][ko];
                accV[ni] = mfma_bf16(aH, vH, accV[ni]);
                accV[ni] = mfma_bf16(aH, vL, accV[ni]);
                accV[ni] = mfma_bf16(aL, vH, accV[ni]);
            }
        }
        __syncthreads();   // all Bop reads done before refresh

        int idx = base + i * estride;
#pragma unroll
        for (int ni = 0; ni < 4; ++ni) {
            int cc = 16 * ni + l15, r0 = 16 * w + 4 * quad;
            *(floatx4*)(PT + (size_t)idx * 4096 + cc * 64 + r0) = accP[ni];
            *(floatx4*)(VT + (size_t)idx * 4096 + cc * 64 + r0) = accV[ni];
            short4v h4, l4;
#pragma unroll
            for (int r = 0; r < 4; ++r) { short hh,ll; split_bf16(accP[ni][r],hh,ll); h4[r]=hh; l4[r]=ll; }
            *(short4v*)&PBh[cc][r0] = h4; *(short4v*)&PBl[cc][r0] = l4;
#pragma unroll
            for (int r = 0; r < 4; ++r) { short hh,ll; split_bf16(accV[ni][r],hh,ll); h4[r]=hh; l4[r]=ll; }
            *(short4v*)&VBh[cc][r0] = h4; *(short4v*)&VBl[cc][r0] = l4;
        }
    }
}

// ---------------------------------------------------------------------------
// S3: 1 block. Over the 8 super aggregates (slots idx=64s+63 after seqscan
// level 2): E_0 = 0; E_{s+1} = P[64s+63]*E_s + V[64s+63]  (V-only recurrence).
// Stores E_{s+1} into the (now dead) PT slot idx=64s+63, in V-layout [b][n].
// ---------------------------------------------------------------------------
__global__ __launch_bounds__(256, 2)
void hippo_s3(float* __restrict__ PT, const float* __restrict__ VT)
{
    __shared__ short PAh[NB][AS], PAl[NB][AS];
    __shared__ short EBh[NB][AS], EBl[NB][AS];
    const int tid = threadIdx.x;
    const int w = tid >> 6, lane = tid & 63, quad = lane >> 4, l15 = lane & 15;

#pragma unroll
    for (int q = 0; q < 16; ++q) {
        int f = tid + q * 256; EBh[f >> 6][f & 63] = 0; EBl[f >> 6][f & 63] = 0;
    }
    for (int s = 0; s < 7; ++s) {
        int idx = 64 * s + 63;
        const float* pc = PT + (size_t)idx * 4096;
        const float* vc = VT + (size_t)idx * 4096;
#pragma unroll
        for (int q = 0; q < 4; ++q) {
            int f = tid + q * 256;
            int k = f & 63, m0 = (f >> 6) * 4;
            float4 v = *(const float4*)(pc + k * 64 + m0);
            float vv[4] = {v.x, v.y, v.z, v.w};
#pragma unroll
            for (int r = 0; r < 4; ++r) {
                short hh, ll; split_bf16(vv[r], hh, ll);
                PAh[m0 + r][k] = hh; PAl[m0 + r][k] = ll;
            }
        }
        floatx4 acc[4];
#pragma unroll
        for (int ni = 0; ni < 4; ++ni) {
            int cc = 16 * ni + l15, r0 = 16 * w + 4 * quad;
            float4 vv = *(const float4*)(vc + cc * 64 + r0);
            acc[ni][0] = vv.x; acc[ni][1] = vv.y; acc[ni][2] = vv.z; acc[ni][3] = vv.w;
        }
        __syncthreads();
#pragma unroll
        for (int kc = 0; kc < 2; ++kc) {
            int ko = 32 * kc + 8 * quad;
            short8 aH = *(const short8*)&PAh[16 * w + l15][ko];
            short8 aL = *(const short8*)&PAl[16 * w + l15][ko];
#pragma unroll
            for (int ni = 0; ni < 4; ++ni) {
                int n = 16 * ni + l15;
                short8 eH = *(const short8*)&EBh[n][ko];
                short8 eL = *(const short8*)&EBl[n][ko];
                acc[ni] = mfma_bf16(aH, eH, acc[ni]);
                acc[ni] = mfma_bf16(aH, eL, acc[ni]);
                acc[ni] = mfma_bf16(aL, eH, acc[ni]);
            }
        }
        __syncthreads();
#pragma unroll
        for (int ni = 0; ni < 4; ++ni) {
            int cc = 16 * ni + l15, r0 = 16 * w + 4 * quad;
            *(floatx4*)(PT + (size_t)idx * 4096 + cc * 64 + r0) = acc[ni];
            short4v h4, l4;
#pragma unroll
            for (int r = 0; r < 4; ++r) { short hh,ll; split_bf16(acc[ni][r],hh,ll); h4[r]=hh; l4[r]=ll; }
            *(short4v*)&EBh[cc][r0] = h4; *(short4v*)&EBl[cc][r0] = l4;
        }
    }
}

// ---------------------------------------------------------------------------
// Phase 3: build entering state E_c from (super E) + (in-super group prefix)
// + (in-group chunk prefix), then x <- A[t] x + u_t for the 8 local steps.
// ---------------------------------------------------------------------------
__global__ __launch_bounds__(256, 2)
void hippo_phase3(const float* __restrict__ inp, const float* __restrict__ Ag,
                  const float* __restrict__ Bst, const float* __restrict__ PT,
                  const float* __restrict__ VT, float* __restrict__ out)
{
    __shared__ short Ah[NB][AS], Al[NB][AS];
    __shared__ short XBh[NB][AS], XBl[NB][AS];
    __shared__ float btl[NB], itl[NB];

    const int tid = threadIdx.x, c = blockIdx.x, t0 = c * CH;
    const int w = tid>>6, lane = tid&63, quad = lane>>4, l15 = lane&15;
    const int sup = c >> 6, g = c >> 3, gi = g & 7, j = c & 7;

    // A prefetch for step 0 issued early (hide HBM under prefix combines)
    float4 pre[4];
    {
        const float4* Ap = (const float4*)(Ag + (size_t)t0 * 4096);
#pragma unroll
        for (int q = 0; q < 4; ++q) pre[q] = Ap[tid + q * 256];
    }

    // ---- entering super state ----
    if (sup == 0) {
#pragma unroll
        for (int q = 0; q < 16; ++q) { int f = tid + q*256; XBh[f>>6][f&63] = 0; XBl[f>>6][f&63] = 0; }
    } else {
        const float* e = PT + (size_t)(64*(sup-1) + 63) * 4096;   // E_sup, V-layout [b][n]
#pragma unroll
        for (int q = 0; q < 4; ++q) {
            int f = tid + q*256; int b = f>>4, k0 = (f&15)*4;
            float4 v = *(const float4*)(e + b*64 + k0);
            float va[4] = {v.x,v.y,v.z,v.w};
            short4v h4, l4;
#pragma unroll
            for (int r=0;r<4;++r){short hh,ll;split_bf16(va[r],hh,ll);h4[r]=hh;l4[r]=ll;}
            *(short4v*)&XBh[b][k0] = h4; *(short4v*)&XBl[b][k0] = l4;
        }
    }

    // ---- apply stored prefixes: X <- P[idx]*X + V[idx] ----
    auto combine = [&](int idx) {
        const float* pc = PT + (size_t)idx * 4096;
        const float* vc = VT + (size_t)idx * 4096;
#pragma unroll
        for (int q = 0; q < 4; ++q) {
            int f = tid + q*256;
            int k = f & 63, m0 = (f>>6)*4;
            float4 v = *(const float4*)(pc + k*64 + m0);
            float vv[4] = {v.x,v.y,v.z,v.w};
#pragma unroll
            for (int r = 0; r < 4; ++r) { short hh,ll; split_bf16(vv[r],hh,ll); Ah[m0+r][k]=hh; Al[m0+r][k]=ll; }
        }
        floatx4 acc[4];
#pragma unroll
        for (int ni = 0; ni < 4; ++ni) {
            int cc = 16*ni + l15, r0 = 16*w + 4*quad;
            float4 vv = *(const float4*)(vc + cc*64 + r0);
            acc[ni][0]=vv.x; acc[ni][1]=vv.y; acc[ni][2]=vv.z; acc[ni][3]=vv.w;
        }
        __syncthreads();
#pragma unroll
        for (int kc = 0; kc < 2; ++kc) {
            int ko = 32*kc + 8*quad;
            short8 aH = *(const short8*)&Ah[16*w + l15][ko];
            short8 aL = *(const short8*)&Al[16*w + l15][ko];
#pragma unroll
            for (int ni = 0; ni < 4; ++ni) {
                int n = 16*ni + l15;
                short8 xH = *(const short8*)&XBh[n][ko];
                short8 xL = *(const short8*)&XBl[n][ko];
                acc[ni] = mfma_bf16(aH, xH, acc[ni]);
                acc[ni] = mfma_bf16(aH, xL, acc[ni]);
                acc[ni] = mfma_bf16(aL, xH, acc[ni]);
            }
        }
        __syncthreads();
#pragma unroll
        for (int ni = 0; ni < 4; ++ni) {
            int cc = 16*ni + l15, r0 = 16*w + 4*quad;
            short4v h4, l4;
#pragma unroll
            for (int r=0;r<4;++r){short hh,ll;split_bf16(acc[ni][r],hh,ll);h4[r]=hh;l4[r]=ll;}
            *(short4v*)&XBh[cc][r0] = h4; *(short4v*)&XBl[cc][r0] = l4;
        }
    };
    if (gi) combine(8*g - 1);   // in-super group prefix (slot ==7 mod 8, S2 output)
    if (j)  combine(c - 1);     // in-group chunk prefix (S1 output)

    // ---- 8 local time steps ----
    floatx4 acc[4];
    for (int s = 0; s < CH; ++s) {
        int t = t0 + s;
#pragma unroll
        for (int q = 0; q < 4; ++q) {
            int f = tid + q*256; int m = f>>4, k0 = (f&15)*4;
            float vv[4] = {pre[q].x,pre[q].y,pre[q].z,pre[q].w};
            short4v h4, l4;
#pragma unroll
            for (int r=0;r<4;++r){short hh,ll;split_bf16(vv[r],hh,ll);h4[r]=hh;l4[r]=ll;}
            *(short4v*)&Ah[m][k0] = h4; *(short4v*)&Al[m][k0] = l4;
        }
        if (tid < 64) { btl[tid] = Bst[(size_t)t*64 + tid]; itl[tid] = inp[(size_t)t*64 + tid]; }
        if (s + 1 < CH) {
            const float4* Ap = (const float4*)(Ag + (size_t)(t+1) * 4096);
#pragma unroll
            for (int q = 0; q < 4; ++q) pre[q] = Ap[tid + q * 256];
        }
        __syncthreads();

#pragma unroll
        for (int ni = 0; ni < 4; ++ni) {
            float ib = itl[16*ni + l15];
#pragma unroll
            for (int r = 0; r < 4; ++r) acc[ni][r] = btl[16*w + 4*quad + r] * ib;
        }
#pragma unroll
        for (int kc = 0; kc < 2; ++kc) {
            int ko = 32*kc + 8*quad;
            short8 aH = *(const short8*)&Ah[16*w + l15][ko];
            short8 aL = *(const short8*)&Al[16*w + l15][ko];
#pragma unroll
            for (int ni = 0; ni < 4; ++ni) {
                int n = 16*ni + l15;
                short8 xH = *(const short8*)&XBh[n][ko];
                short8 xL = *(const short8*)&XBl[n][ko];
                acc[ni] = mfma_bf16(aH, xH, acc[ni]);
                acc[ni] = mfma_bf16(aH, xL, acc[ni]);
                acc[ni] = mfma_bf16(aL, xH, acc[ni]);
            }
        }
        __syncthreads();
#pragma unroll
        for (int ni = 0; ni < 4; ++ni) {
            int cc = 16*ni + l15, r0 = 16*w + 4*quad;
            *(floatx4*)(out + (size_t)t*4096 + cc*64 + r0) = acc[ni];   // out[t][b][n0..3]
            if (s + 1 < CH) {
                short4v h4, l4;
#pragma unroll
                for (int r=0;r<4;++r){short hh,ll;split_bf16(acc[ni][r],hh,ll);h4[r]=hh;l4[r]=ll;}
                *(short4v*)&XBh[cc][r0] = h4; *(short4v*)&XBl[cc][r0] = l4;
            }
        }
    }
}

extern "C" void kernel_launch(void* const* d_in, const int* in_sizes, int n_in,
                              void* d_out, int out_size, void* d_ws, size_t ws_size,
                              hipStream_t stream)
{
    const float* inp = (const float*)d_in[0];   // (L, B)
    const float* A   = (const float*)d_in[1];   // (L, N, N)
    const float* Bst = (const float*)d_in[2];   // (L, N)
    float* out = (float*)d_out;                  // (L, B, N)
    float* ws  = (float*)d_ws;                   // 16 MB used

    float* PT = ws;
    float* VT = ws + (size_t)CN * 4096;

    hippo_phase1<<<CN, 256, 0, stream>>>(inp, A, Bst, PT, VT);
    // level 1: in-group prefixes (64 groups of 8 chunks), in place
    hippo_seqscan<<<64, 256, 0, stream>>>(PT, VT, 8, 0, 1);
    // level 2: in-super prefixes over group aggregates (slots ==7 mod 8)
    hippo_seqscan<<<8, 256, 0, stream>>>(PT, VT, 64, 7, 8);
    // level 3: entering super states -> dead PT slots at idx 64s+63
    hippo_s3<<<1, 256, 0, stream>>>(PT, VT);
    hippo_phase3<<<CN, 256, 0, stream>>>(inp, A, Bst, PT, VT, out);
}

// Round 2
// 184.040 us; speedup vs baseline: 1.2746x; 1.1333x over previous
//
#include <hip/hip_runtime.h>
#include <hip/hip_bf16.h>

// L=4096, N=B=64. CH=8 -> CN=512 chunks (2 WG/CU on 256 CUs).
// Scan hierarchy: 512 chunks = 64 groups x 8 = 8 supers x 8 groups x 8.
// P (chunk A-products) stored ROW-MAJOR as packed (hi<<16)|lo bf16 u32 ->
// Aop staging is contiguous loads + 2-op unpack (no b16 scatter).
// V stored fp32 transposed (Bop staging + C-init friendly).
#define TL 4096
#define NB 64
#define CH 8
#define CN 512
#define AS 72          // LDS row stride (bf16 elems): 144 B = 9 x 16B groups (odd -> conflict-free b128)

typedef __attribute__((ext_vector_type(8))) short short8;   // 8 x bf16 MFMA frag
typedef __attribute__((ext_vector_type(4))) short short4v;  // 4 x bf16 (b64 store)
typedef __attribute__((ext_vector_type(4))) float floatx4;  // MFMA acc
typedef __attribute__((ext_vector_type(4))) unsigned int uint4v;

__device__ inline floatx4 mfma_bf16(short8 a, short8 b, floatx4 c) {
    return __builtin_amdgcn_mfma_f32_16x16x32_bf16(a, b, c, 0, 0, 0);
}

// RNE f32->bf16 via hardware cvt (pairs into v_cvt_pk_bf16_f32).
__device__ inline short bf16_rne(float x) {
    union { __hip_bfloat16 b; unsigned short s; } u;
    u.b = __float2bfloat16(x);
    return (short)u.s;
}

// fp32 -> (hi, lo) bf16 pair. x ~= hi + lo to ~2^-17 rel. ~4 VALU ops.
__device__ inline void split_bf16(float x, short& h, short& l) {
    h = bf16_rne(x);
    union { unsigned u; float f; } hv; hv.u = ((unsigned)(unsigned short)h) << 16;
    l = bf16_rne(x - hv.f);
}

// ---------------------------------------------------------------------------
// Phase 1 (forward): per chunk c, S <- A[t]*S (S0=I), V <- A[t]*V + b_t (x) i_t.
// Emits P32[c] = S row-major packed hi|lo, VT[c] = V^T fp32.
// ---------------------------------------------------------------------------
__global__ __launch_bounds__(256, 2)
void hippo_phase1(const float* __restrict__ inp, const float* __restrict__ Ag,
                  const float* __restrict__ Bst,
                  unsigned* __restrict__ P32, float* __restrict__ VT)
{
    __shared__ short Ah[NB][AS], Al[NB][AS];
    __shared__ short SBh[NB][AS], SBl[NB][AS];
    __shared__ short VBh[NB][AS], VBl[NB][AS];
    __shared__ float btl[NB], itl[NB];

    const int tid  = threadIdx.x;
    const int c    = blockIdx.x;
    const int t0   = c * CH;
    const int w    = tid >> 6, lane = tid & 63;
    const int quad = lane >> 4, l15 = lane & 15;

    // SB = I (bf16(1.0) = 0x3F80), VB = 0
#pragma unroll
    for (int q = 0; q < 16; ++q) {
        int f = tid + q * 256;
        int n = f >> 6, k = f & 63;
        SBh[n][k] = (n == k) ? (short)0x3F80 : (short)0;
        SBl[n][k] = 0; VBh[n][k] = 0; VBl[n][k] = 0;
    }

    float4 pre[4];
    {
        const float4* Ap = (const float4*)(Ag + (size_t)t0 * 4096);
#pragma unroll
        for (int q = 0; q < 4; ++q) pre[q] = Ap[tid + q * 256];
    }

    floatx4 accS[4], accV[4];

    for (int s = 0; s < CH; ++s) {
        int t = t0 + s;
#pragma unroll
        for (int q = 0; q < 4; ++q) {
            int f = tid + q * 256;
            int m = f >> 4, k0 = (f & 15) * 4;
            float vv[4] = {pre[q].x, pre[q].y, pre[q].z, pre[q].w};
            short4v h4, l4;
#pragma unroll
            for (int r = 0; r < 4; ++r) { short hh, ll; split_bf16(vv[r], hh, ll); h4[r]=hh; l4[r]=ll; }
            *(short4v*)&Ah[m][k0] = h4;
            *(short4v*)&Al[m][k0] = l4;
        }
        if (tid < 64) { btl[tid] = Bst[(size_t)t*64 + tid]; itl[tid] = inp[(size_t)t*64 + tid]; }
        if (s + 1 < CH) {
            const float4* Ap = (const float4*)(Ag + (size_t)(t+1) * 4096);
#pragma unroll
            for (int q = 0; q < 4; ++q) pre[q] = Ap[tid + q * 256];
        }
        __syncthreads();   // A, btl/itl, prev SB/VB visible

#pragma unroll
        for (int ni = 0; ni < 4; ++ni) {
            float ib = itl[16*ni + l15];
#pragma unroll
            for (int r = 0; r < 4; ++r) {
                accS[ni][r] = 0.0f;
                accV[ni][r] = btl[16*w + 4*quad + r] * ib;   // u_t = b_t (x) i_t in C-layout
            }
        }
#pragma unroll
        for (int kc = 0; kc < 2; ++kc) {
            int ko = 32*kc + 8*quad;
            short8 aH = *(const short8*)&Ah[16*w + l15][ko];
            short8 aL = *(const short8*)&Al[16*w + l15][ko];
#pragma unroll
            for (int ni = 0; ni < 4; ++ni) {
                int n = 16*ni + l15;
                short8 sH = *(const short8*)&SBh[n][ko];
                short8 sL = *(const short8*)&SBl[n][ko];
                accS[ni] = mfma_bf16(aH, sH, accS[ni]);
                accS[ni] = mfma_bf16(aH, sL, accS[ni]);
                accS[ni] = mfma_bf16(aL, sH, accS[ni]);
                short8 vH = *(const short8*)&VBh[n][ko];
                short8 vL = *(const short8*)&VBl[n][ko];
                accV[ni] = mfma_bf16(aH, vH, accV[ni]);
                accV[ni] = mfma_bf16(aH, vL, accV[ni]);
                accV[ni] = mfma_bf16(aL, vH, accV[ni]);
            }
        }
        __syncthreads();   // all SB/VB reads done

        if (s + 1 < CH) {
#pragma unroll
            for (int ni = 0; ni < 4; ++ni) {
                int cc = 16*ni + l15, r0 = 16*w + 4*quad;
                short4v h4, l4;
#pragma unroll
                for (int r = 0; r < 4; ++r) { short hh,ll; split_bf16(accS[ni][r],hh,ll); h4[r]=hh; l4[r]=ll; }
                *(short4v*)&SBh[cc][r0] = h4; *(short4v*)&SBl[cc][r0] = l4;
#pragma unroll
                for (int r = 0; r < 4; ++r) { short hh,ll; split_bf16(accV[ni][r],hh,ll); h4[r]=hh; l4[r]=ll; }
                *(short4v*)&VBh[cc][r0] = h4; *(short4v*)&VBl[cc][r0] = l4;
            }
        }
    }
    // final aggregates: V^T fp32 (float4), S row-major packed hi|lo u32.
    unsigned* po = P32 + (size_t)c * 4096;
#pragma unroll
    for (int ni = 0; ni < 4; ++ni) {
        int cc = 16*ni + l15, r0 = 16*w + 4*quad;
        *(floatx4*)(VT + (size_t)c*4096 + cc*64 + r0) = accV[ni];
#pragma unroll
        for (int r = 0; r < 4; ++r) {
            short hh, ll; split_bf16(accS[ni][r], hh, ll);
            po[(r0 + r)*64 + cc] = ((unsigned)(unsigned short)hh << 16) | (unsigned)(unsigned short)ll;
        }
    }
}

// ---------------------------------------------------------------------------
// Sequential in-place scan of 8 elements per block.
// Elements at chunk idx = blockIdx.x*bstride + off0 + i*estride, i=0..7.
// Slot i <- inclusive prefix over elements 0..i.  Pnew = P_i*Pacc (Aop=P_i),
// Vnew = P_i*Vacc + V_i.
// ---------------------------------------------------------------------------
__global__ __launch_bounds__(256, 2)
void hippo_seqscan(unsigned* __restrict__ P32, float* __restrict__ VT,
                   int bstride, int off0, int estride)
{
    __shared__ short PAh[NB][AS], PAl[NB][AS];   // P_i row-major (Aop)
    __shared__ short PBh[NB][AS], PBl[NB][AS];   // Pacc^T (Bop)
    __shared__ short VBh[NB][AS], VBl[NB][AS];   // Vacc^T (Bop)

    const int tid  = threadIdx.x;
    const int base = blockIdx.x * bstride + off0;
    const int w    = tid >> 6, lane = tid & 63;
    const int quad = lane >> 4, l15 = lane & 15;

    // element 0 -> Bop LDS. P: packed row-major -> scatter-transpose (once).
    // V: fp32 transposed -> direct row copy + split.
    {
        const unsigned* p0 = P32 + (size_t)base * 4096;
        const float*    v0 = VT  + (size_t)base * 4096;
#pragma unroll
        for (int q = 0; q < 4; ++q) {
            int f = tid + q * 256;
            int k = f & 63, m0 = (f >> 6) * 4;
            uint4v pk = *(const uint4v*)(p0 + k * 64 + m0);
#pragma unroll
            for (int r = 0; r < 4; ++r) {
                PBh[m0 + r][k] = (short)(pk[r] >> 16);
                PBl[m0 + r][k] = (short)(pk[r] & 0xFFFFu);
            }
        }
#pragma unroll
        for (int q = 0; q < 4; ++q) {
            int f = tid + q * 256;
            int n = f >> 4, k0 = (f & 15) * 4;
            float4 vv = *(const float4*)(v0 + n * 64 + k0);
            float va[4] = {vv.x, vv.y, vv.z, vv.w};
            short4v vh4, vl4;
#pragma unroll
            for (int r = 0; r < 4; ++r) { short hh, ll; split_bf16(va[r], hh, ll); vh4[r]=hh; vl4[r]=ll; }
            *(short4v*)&VBh[n][k0] = vh4; *(short4v*)&VBl[n][k0] = vl4;
        }
    }

    // prefetch element 1 (packed rows + C-layout V)
    uint4v preA[4]; float4 preV[4];
    {
        const unsigned* pc = P32 + (size_t)(base + estride) * 4096;
        const float*    vc = VT  + (size_t)(base + estride) * 4096;
#pragma unroll
        for (int q = 0; q < 4; ++q) {
            int f = tid + q * 256;
            int m = f >> 4, k0 = (f & 15) * 4;
            preA[q] = *(const uint4v*)(pc + m * 64 + k0);
        }
#pragma unroll
        for (int ni = 0; ni < 4; ++ni) {
            int cc = 16 * ni + l15, r0 = 16 * w + 4 * quad;
            preV[ni] = *(const float4*)(vc + cc * 64 + r0);
        }
    }

    for (int i = 1; i < 8; ++i) {
        // stage Aop = P_i: unpack packed pairs, contiguous b64 writes
#pragma unroll
        for (int q = 0; q < 4; ++q) {
            int f = tid + q * 256;
            int m = f >> 4, k0 = (f & 15) * 4;
            short4v h4, l4;
#pragma unroll
            for (int r = 0; r < 4; ++r) { h4[r] = (short)(preA[q][r] >> 16); l4[r] = (short)(preA[q][r] & 0xFFFFu); }
            *(short4v*)&PAh[m][k0] = h4;
            *(short4v*)&PAl[m][k0] = l4;
        }
        floatx4 accP[4], accV[4];
#pragma unroll
        for (int ni = 0; ni < 4; ++ni) {
            accV[ni][0] = preV[ni].x; accV[ni][1] = preV[ni].y;
            accV[ni][2] = preV[ni].z; accV[ni][3] = preV[ni].w;
            accP[ni][0] = accP[ni][1] = accP[ni][2] = accP[ni][3] = 0.0f;
        }
        if (i + 1 < 8) {   // prefetch next element
            const unsigned* pc = P32 + (size_t)(base + (i + 1) * estride) * 4096;
            const float*    vc = VT  + (size_t)(base + (i + 1) * estride) * 4096;
#pragma unroll
            for (int q = 0; q < 4; ++q) {
                int f = tid + q * 256;
                int m = f >> 4, k0 = (f & 15) * 4;
                preA[q] = *(const uint4v*)(pc + m * 64 + k0);
            }
#pragma unroll
            for (int ni = 0; ni < 4; ++ni) {
                int cc = 16 * ni + l15, r0 = 16 * w + 4 * quad;
                preV[ni] = *(const float4*)(vc + cc * 64 + r0);
            }
        }
        __syncthreads();   // PA + (PB/VB from prev iter) visible

#pragma unroll
        for (int kc = 0; kc < 2; ++kc) {
            int ko = 32 * kc + 8 * quad;
            short8 aH = *(const short8*)&PAh[16 * w + l15][ko];
            short8 aL = *(const short8*)&PAl[16 * w + l15][ko];
#pragma unroll
            for (int ni = 0; ni < 4; ++ni) {
                int n = 16 * ni + l15;
                short8 pH = *(const short8*)&PBh[n][ko];
                short8 pL = *(const short8*)&PBl[n][ko];
                accP[ni] = mfma_bf16(aH, pH, accP[ni]);
                accP[ni] = mfma_bf16(aH, pL, accP[ni]);
                accP[ni] = mfma_bf16(aL, pH, accP[ni]);
                short8 vH = *(const short8*)&VBh[n][ko];
                short8 vL = *(const short8*)&VBl[n][ko];
                accV[ni] = mfma_bf16(aH, vH, accV[ni]);
                accV[ni] = mfma_bf16(aH, vL, accV[ni]);
                accV[ni] = mfma_bf16(aL, vH, accV[ni]);
            }
        }
        __syncthreads();   // all Bop reads done before refresh

        int idx = base + i * estride;
        unsigned* po = P32 + (size_t)idx * 4096;
#pragma unroll
        for (int ni = 0; ni < 4; ++ni) {
            int cc = 16 * ni + l15, r0 = 16 * w + 4 * quad;
            *(floatx4*)(VT + (size_t)idx * 4096 + cc * 64 + r0) = accV[ni];
            short4v h4, l4;
#pragma unroll
            for (int r = 0; r < 4; ++r) {
                short hh, ll; split_bf16(accP[ni][r], hh, ll);
                po[(r0 + r) * 64 + cc] = ((unsigned)(unsigned short)hh << 16) | (unsigned)(unsigned short)ll;
                h4[r] = hh; l4[r] = ll;
            }
            *(short4v*)&PBh[cc][r0] = h4; *(short4v*)&PBl[cc][r0] = l4;
#pragma unroll
            for (int r = 0; r < 4; ++r) { short hh,ll; split_bf16(accV[ni][r],hh,ll); h4[r]=hh; l4[r]=ll; }
            *(short4v*)&VBh[cc][r0] = h4; *(short4v*)&VBl[cc][r0] = l4;
        }
    }
}

// ---------------------------------------------------------------------------
// S3: 1 block. Over the 8 super aggregates (slots idx=64s+63 after seqscan
// level 2): E_0 = 0; E_{s+1} = P[64s+63]*E_s + V[64s+63]  (V-only recurrence).
// Stores E_{s+1} fp32 into the (now dead) P32 slot idx=64s+63, layout [b][n].
// ---------------------------------------------------------------------------
__global__ __launch_bounds__(256, 2)
void hippo_s3(unsigned* __restrict__ P32, const float* __restrict__ VT)
{
    __shared__ short PAh[NB][AS], PAl[NB][AS];
    __shared__ short EBh[NB][AS], EBl[NB][AS];
    const int tid = threadIdx.x;
    const int w = tid >> 6, lane = tid & 63, quad = lane >> 4, l15 = lane & 15;

#pragma unroll
    for (int q = 0; q < 16; ++q) {
        int f = tid + q * 256; EBh[f >> 6][f & 63] = 0; EBl[f >> 6][f & 63] = 0;
    }
    for (int s = 0; s < 7; ++s) {
        int idx = 64 * s + 63;
        const unsigned* pc = P32 + (size_t)idx * 4096;
        const float*    vc = VT  + (size_t)idx * 4096;
#pragma unroll
        for (int q = 0; q < 4; ++q) {
            int f = tid + q * 256;
            int m = f >> 4, k0 = (f & 15) * 4;
            uint4v pk = *(const uint4v*)(pc + m * 64 + k0);
            short4v h4, l4;
#pragma unroll
            for (int r = 0; r < 4; ++r) { h4[r] = (short)(pk[r] >> 16); l4[r] = (short)(pk[r] & 0xFFFFu); }
            *(short4v*)&PAh[m][k0] = h4;
            *(short4v*)&PAl[m][k0] = l4;
        }
        floatx4 acc[4];
#pragma unroll
        for (int ni = 0; ni < 4; ++ni) {
            int cc = 16 * ni + l15, r0 = 16 * w + 4 * quad;
            float4 vv = *(const float4*)(vc + cc * 64 + r0);
            acc[ni][0] = vv.x; acc[ni][1] = vv.y; acc[ni][2] = vv.z; acc[ni][3] = vv.w;
        }
        __syncthreads();
#pragma unroll
        for (int kc = 0; kc < 2; ++kc) {
            int ko = 32 * kc + 8 * quad;
            short8 aH = *(const short8*)&PAh[16 * w + l15][ko];
            short8 aL = *(const short8*)&PAl[16 * w + l15][ko];
#pragma unroll
            for (int ni = 0; ni < 4; ++ni) {
                int n = 16 * ni + l15;
                short8 eH = *(const short8*)&EBh[n][ko];
                short8 eL = *(const short8*)&EBl[n][ko];
                acc[ni] = mfma_bf16(aH, eH, acc[ni]);
                acc[ni] = mfma_bf16(aH, eL, acc[ni]);
                acc[ni] = mfma_bf16(aL, eH, acc[ni]);
            }
        }
        __syncthreads();
        float* eo = (float*)(P32 + (size_t)idx * 4096);
#pragma unroll
        for (int ni = 0; ni < 4; ++ni) {
            int cc = 16 * ni + l15, r0 = 16 * w + 4 * quad;
            *(floatx4*)(eo + cc * 64 + r0) = acc[ni];
            short4v h4, l4;
#pragma unroll
            for (int r = 0; r < 4; ++r) { short hh,ll; split_bf16(acc[ni][r],hh,ll); h4[r]=hh; l4[r]=ll; }
            *(short4v*)&EBh[cc][r0] = h4; *(short4v*)&EBl[cc][r0] = l4;
        }
    }
}

// ---------------------------------------------------------------------------
// Phase 3: build entering state E_c from (super E) + (in-super group prefix)
// + (in-group chunk prefix), then x <- A[t] x + u_t for the 8 local steps.
// ---------------------------------------------------------------------------
__global__ __launch_bounds__(256, 2)
void hippo_phase3(const float* __restrict__ inp, const float* __restrict__ Ag,
                  const float* __restrict__ Bst, const unsigned* __restrict__ P32,
                  const float* __restrict__ VT, float* __restrict__ out)
{
    __shared__ short Ah[NB][AS], Al[NB][AS];
    __shared__ short XBh[NB][AS], XBl[NB][AS];
    __shared__ float btl[NB], itl[NB];

    const int tid = threadIdx.x, c = blockIdx.x, t0 = c * CH;
    const int w = tid>>6, lane = tid&63, quad = lane>>4, l15 = lane&15;
    const int sup = c >> 6, g = c >> 3, gi = g & 7, j = c & 7;

    // A prefetch for step 0 issued early (hide HBM under prefix combines)
    float4 pre[4];
    {
        const float4* Ap = (const float4*)(Ag + (size_t)t0 * 4096);
#pragma unroll
        for (int q = 0; q < 4; ++q) pre[q] = Ap[tid + q * 256];
    }

    // ---- entering super state ----
    if (sup == 0) {
#pragma unroll
        for (int q = 0; q < 16; ++q) { int f = tid + q*256; XBh[f>>6][f&63] = 0; XBl[f>>6][f&63] = 0; }
    } else {
        const float* e = (const float*)(P32 + (size_t)(64*(sup-1) + 63) * 4096);  // E_sup [b][n] fp32
#pragma unroll
        for (int q = 0; q < 4; ++q) {
            int f = tid + q*256; int b = f>>4, k0 = (f&15)*4;
            float4 v = *(const float4*)(e + b*64 + k0);
            float va[4] = {v.x,v.y,v.z,v.w};
            short4v h4, l4;
#pragma unroll
            for (int r=0;r<4;++r){short hh,ll;split_bf16(va[r],hh,ll);h4[r]=hh;l4[r]=ll;}
            *(short4v*)&XBh[b][k0] = h4; *(short4v*)&XBl[b][k0] = l4;
        }
    }

    // ---- apply stored prefixes: X <- P[idx]*X + V[idx] ----
    auto combine = [&](int idx) {
        const unsigned* pc = P32 + (size_t)idx * 4096;
        const float*    vc = VT  + (size_t)idx * 4096;
#pragma unroll
        for (int q = 0; q < 4; ++q) {
            int f = tid + q*256;
            int m = f >> 4, k0 = (f & 15) * 4;
            uint4v pk = *(const uint4v*)(pc + m * 64 + k0);
            short4v h4, l4;
#pragma unroll
            for (int r = 0; r < 4; ++r) { h4[r] = (short)(pk[r] >> 16); l4[r] = (short)(pk[r] & 0xFFFFu); }
            *(short4v*)&Ah[m][k0] = h4;
            *(short4v*)&Al[m][k0] = l4;
        }
        floatx4 acc[4];
#pragma unroll
        for (int ni = 0; ni < 4; ++ni) {
            int cc = 16*ni + l15, r0 = 16*w + 4*quad;
            float4 vv = *(const float4*)(vc + cc*64 + r0);
            acc[ni][0]=vv.x; acc[ni][1]=vv.y; acc[ni][2]=vv.z; acc[ni][3]=vv.w;
        }
        __syncthreads();
#pragma unroll
        for (int kc = 0; kc < 2; ++kc) {
            int ko = 32*kc + 8*quad;
            short8 aH = *(const short8*)&Ah[16*w + l15][ko];
            short8 aL = *(const short8*)&Al[16*w + l15][ko];
#pragma unroll
            for (int ni = 0; ni < 4; ++ni) {
                int n = 16*ni + l15;
                short8 xH = *(const short8*)&XBh[n][ko];
                short8 xL = *(const short8*)&XBl[n][ko];
                acc[ni] = mfma_bf16(aH, xH, acc[ni]);
                acc[ni] = mfma_bf16(aH, xL, acc[ni]);
                acc[ni] = mfma_bf16(aL, xH, acc[ni]);
            }
        }
        __syncthreads();
#pragma unroll
        for (int ni = 0; ni < 4; ++ni) {
            int cc = 16*ni + l15, r0 = 16*w + 4*quad;
            short4v h4, l4;
#pragma unroll
            for (int r=0;r<4;++r){short hh,ll;split_bf16(acc[ni][r],hh,ll);h4[r]=hh;l4[r]=ll;}
            *(short4v*)&XBh[cc][r0] = h4; *(short4v*)&XBl[cc][r0] = l4;
        }
    };
    if (gi) combine(8*g - 1);   // in-super group prefix (slot ==7 mod 8, S2 output)
    if (j)  combine(c - 1);     // in-group chunk prefix (S1 output)

    // ---- 8 local time steps ----
    floatx4 acc[4];
    for (int s = 0; s < CH; ++s) {
        int t = t0 + s;
#pragma unroll
        for (int q = 0; q < 4; ++q) {
            int f = tid + q*256; int m = f>>4, k0 = (f&15)*4;
            float vv[4] = {pre[q].x,pre[q].y,pre[q].z,pre[q].w};
            short4v h4, l4;
#pragma unroll
            for (int r=0;r<4;++r){short hh,ll;split_bf16(vv[r],hh,ll);h4[r]=hh;l4[r]=ll;}
            *(short4v*)&Ah[m][k0] = h4; *(short4v*)&Al[m][k0] = l4;
        }
        if (tid < 64) { btl[tid] = Bst[(size_t)t*64 + tid]; itl[tid] = inp[(size_t)t*64 + tid]; }
        if (s + 1 < CH) {
            const float4* Ap = (const float4*)(Ag + (size_t)(t+1) * 4096);
#pragma unroll
            for (int q = 0; q < 4; ++q) pre[q] = Ap[tid + q * 256];
        }
        __syncthreads();

#pragma unroll
        for (int ni = 0; ni < 4; ++ni) {
            float ib = itl[16*ni + l15];
#pragma unroll
            for (int r = 0; r < 4; ++r) acc[ni][r] = btl[16*w + 4*quad + r] * ib;
        }
#pragma unroll
        for (int kc = 0; kc < 2; ++kc) {
            int ko = 32*kc + 8*quad;
            short8 aH = *(const short8*)&Ah[16*w + l15][ko];
            short8 aL = *(const short8*)&Al[16*w + l15][ko];
#pragma unroll
            for (int ni = 0; ni < 4; ++ni) {
                int n = 16*ni + l15;
                short8 xH = *(const short8*)&XBh[n][ko];
                short8 xL = *(const short8*)&XBl[n][ko];
                acc[ni] = mfma_bf16(aH, xH, acc[ni]);
                acc[ni] = mfma_bf16(aH, xL, acc[ni]);
                acc[ni] = mfma_bf16(aL, xH, acc[ni]);
            }
        }
        __syncthreads();
#pragma unroll
        for (int ni = 0; ni < 4; ++ni) {
            int cc = 16*ni + l15, r0 = 16*w + 4*quad;
            *(floatx4*)(out + (size_t)t*4096 + cc*64 + r0) = acc[ni];   // out[t][b][n0..3]
            if (s + 1 < CH) {
                short4v h4, l4;
#pragma unroll
                for (int r=0;r<4;++r){short hh,ll;split_bf16(acc[ni][r],hh,ll);h4[r]=hh;l4[r]=ll;}
                *(short4v*)&XBh[cc][r0] = h4; *(short4v*)&XBl[cc][r0] = l4;
            }
        }
    }
}

extern "C" void kernel_launch(void* const* d_in, const int* in_sizes, int n_in,
                              void* d_out, int out_size, void* d_ws, size_t ws_size,
                              hipStream_t stream)
{
    const float* inp = (const float*)d_in[0];   // (L, B)
    const float* A   = (const float*)d_in[1];   // (L, N, N)
    const float* Bst = (const float*)d_in[2];   // (L, N)
    float* out = (float*)d_out;                  // (L, B, N)
    float* ws  = (float*)d_ws;                   // 16 MB used

    unsigned* P32 = (unsigned*)ws;               // 8 MB: packed hi|lo, row-major
    float*    VT  = ws + (size_t)CN * 4096;      // 8 MB: fp32, transposed

    hippo_phase1<<<CN, 256, 0, stream>>>(inp, A, Bst, P32, VT);
    // level 1: in-group prefixes (64 groups of 8 chunks), in place
    hippo_seqscan<<<64, 256, 0, stream>>>(P32, VT, 8, 0, 1);
    // level 2: in-super prefixes over group aggregates (slots ==7 mod 8)
    hippo_seqscan<<<8, 256, 0, stream>>>(P32, VT, 64, 7, 8);
    // level 3: entering super states -> dead P32 slots at idx 64s+63
    hippo_s3<<<1, 256, 0, stream>>>(P32, VT);
    hippo_phase3<<<CN, 256, 0, stream>>>(inp, A, Bst, P32, VT, out);
}

// Round 3
// 180.071 us; speedup vs baseline: 1.3027x; 1.0220x over previous
//
#include <hip/hip_runtime.h>
#include <hip/hip_bf16.h>

// L=4096, N=B=64. CH=8 -> CN=512 chunks (2 WG/CU on 256 CUs).
// Scan hierarchy: 512 chunks = 64 groups x 8 = 8 supers x 8 groups x 8.
// P stored ROW-MAJOR packed (hi<<16)|lo bf16 u32; V stored fp32 transposed.
// Warp tiling: 2x2 warp grid, each warp owns a 32(m) x 32(b) output tile ->
// each wave reads only its 32-row A slice and 32-col state slice from LDS.
#define TL 4096
#define NB 64
#define CH 8
#define CN 512
#define AS 72          // LDS row stride (bf16): 144 B = 9 x 16B (odd -> conflict-free b128)

typedef __attribute__((ext_vector_type(8))) short short8;
typedef __attribute__((ext_vector_type(4))) short short4v;
typedef __attribute__((ext_vector_type(4))) float floatx4;
typedef __attribute__((ext_vector_type(4))) unsigned int uint4v;

__device__ inline floatx4 mfma_bf16(short8 a, short8 b, floatx4 c) {
    return __builtin_amdgcn_mfma_f32_16x16x32_bf16(a, b, c, 0, 0, 0);
}

__device__ inline short bf16_rne(float x) {
    union { __hip_bfloat16 b; unsigned short s; } u;
    u.b = __float2bfloat16(x);
    return (short)u.s;
}

// fp32 -> (hi, lo) bf16 pair. x ~= hi + lo to ~2^-17 rel.
__device__ inline void split_bf16(float x, short& h, short& l) {
    h = bf16_rne(x);
    union { unsigned u; float f; } hv; hv.u = ((unsigned)(unsigned short)h) << 16;
    l = bf16_rne(x - hv.f);
}

// ---------------------------------------------------------------------------
// Phase 1: per chunk c, S <- A[t]*S (S0=I), V <- A[t]*V + b_t (x) i_t.
// Step 0 computed directly (S=A[t0] exact, V=u0), steps 1..7 via MFMA.
// Emits P32[c] = S row-major packed hi|lo, VT[c] = V^T fp32.
// ---------------------------------------------------------------------------
__global__ __launch_bounds__(256, 2)
void hippo_phase1(const float* __restrict__ inp, const float* __restrict__ Ag,
                  const float* __restrict__ Bst,
                  unsigned* __restrict__ P32, float* __restrict__ VT)
{
    __shared__ short Ah[NB][AS], Al[NB][AS];
    __shared__ short SBh[NB][AS], SBl[NB][AS];
    __shared__ short VBh[NB][AS], VBl[NB][AS];

    const int tid = threadIdx.x;
    const int c = blockIdx.x, t0 = c * CH;
    const int w = tid >> 6, lane = tid & 63;
    const int quad = lane >> 4, l15 = lane & 15;
    const int wm = w >> 1, wb = w & 1;
    const int mr0 = 32*wm, br0 = 32*wb;

    floatx4 accS[2][2], accV[2][2];

    // ---- s = 0 direct: S = A[t0] (exact fp32), V = b0 (x) i0 ----
    {
        const float* A0 = Ag + (size_t)t0 * 4096;
#pragma unroll
        for (int mi = 0; mi < 2; ++mi) {
            const int r0 = mr0 + 16*mi + 4*quad;
            float bt[4];
#pragma unroll
            for (int r = 0; r < 4; ++r) bt[r] = Bst[(size_t)t0*64 + r0 + r];
#pragma unroll
            for (int ni = 0; ni < 2; ++ni) {
                const int cc = br0 + 16*ni + l15;
                const float ii = inp[(size_t)t0*64 + cc];
#pragma unroll
                for (int r = 0; r < 4; ++r) {
                    accS[mi][ni][r] = A0[(size_t)(r0 + r)*64 + cc];
                    accV[mi][ni][r] = bt[r] * ii;
                }
            }
        }
    }

    // prefetch A[t0+1] and b/i[t0+1]
    float4 pre[4];
    float preB[2][4], preI[2];
    {
        const float4* Ap = (const float4*)(Ag + (size_t)(t0+1) * 4096);
#pragma unroll
        for (int q = 0; q < 4; ++q) pre[q] = Ap[tid + q*256];
#pragma unroll
        for (int mi = 0; mi < 2; ++mi)
#pragma unroll
            for (int r = 0; r < 4; ++r)
                preB[mi][r] = Bst[(size_t)(t0+1)*64 + mr0 + 16*mi + 4*quad + r];
        preI[0] = inp[(size_t)(t0+1)*64 + br0 + l15];
        preI[1] = inp[(size_t)(t0+1)*64 + br0 + 16 + l15];
    }

    // writeback s=0 state (reads happen only after the next barrier)
#pragma unroll
    for (int mi = 0; mi < 2; ++mi)
#pragma unroll
    for (int ni = 0; ni < 2; ++ni) {
        const int cc = br0 + 16*ni + l15, r0 = mr0 + 16*mi + 4*quad;
        short4v h4, l4;
#pragma unroll
        for (int r = 0; r < 4; ++r) { short hh,ll; split_bf16(accS[mi][ni][r],hh,ll); h4[r]=hh; l4[r]=ll; }
        *(short4v*)&SBh[cc][r0] = h4; *(short4v*)&SBl[cc][r0] = l4;
#pragma unroll
        for (int r = 0; r < 4; ++r) { short hh,ll; split_bf16(accV[mi][ni][r],hh,ll); h4[r]=hh; l4[r]=ll; }
        *(short4v*)&VBh[cc][r0] = h4; *(short4v*)&VBl[cc][r0] = l4;
    }

    for (int s = 1; s < CH; ++s) {
        // stage A[t0+s]
#pragma unroll
        for (int q = 0; q < 4; ++q) {
            int f = tid + q*256;
            int m = f >> 4, k0 = (f & 15)*4;
            float vv[4] = {pre[q].x, pre[q].y, pre[q].z, pre[q].w};
            short4v h4, l4;
#pragma unroll
            for (int r = 0; r < 4; ++r) { short hh,ll; split_bf16(vv[r],hh,ll); h4[r]=hh; l4[r]=ll; }
            *(short4v*)&Ah[m][k0] = h4; *(short4v*)&Al[m][k0] = l4;
        }
        float bcur[2][4], icur[2];
#pragma unroll
        for (int mi=0;mi<2;++mi)
#pragma unroll
            for (int r=0;r<4;++r) bcur[mi][r] = preB[mi][r];
        icur[0]=preI[0]; icur[1]=preI[1];
        if (s + 1 < CH) {
            const int t1 = t0 + s + 1;
            const float4* Ap = (const float4*)(Ag + (size_t)t1 * 4096);
#pragma unroll
            for (int q = 0; q < 4; ++q) pre[q] = Ap[tid + q*256];
#pragma unroll
            for (int mi=0;mi<2;++mi)
#pragma unroll
                for (int r=0;r<4;++r)
                    preB[mi][r] = Bst[(size_t)t1*64 + mr0 + 16*mi + 4*quad + r];
            preI[0] = inp[(size_t)t1*64 + br0 + l15];
            preI[1] = inp[(size_t)t1*64 + br0 + 16 + l15];
        }
        __syncthreads();   // A + prev state visible

#pragma unroll
        for (int mi=0;mi<2;++mi)
#pragma unroll
        for (int ni=0;ni<2;++ni)
#pragma unroll
        for (int r=0;r<4;++r) {
            accS[mi][ni][r] = 0.0f;
            accV[mi][ni][r] = bcur[mi][r] * icur[ni];
        }
#pragma unroll
        for (int kc = 0; kc < 2; ++kc) {
            const int ko = 32*kc + 8*quad;
            short8 aH0 = *(const short8*)&Ah[mr0 + l15][ko];
            short8 aL0 = *(const short8*)&Al[mr0 + l15][ko];
            short8 aH1 = *(const short8*)&Ah[mr0 + 16 + l15][ko];
            short8 aL1 = *(const short8*)&Al[mr0 + 16 + l15][ko];
#pragma unroll
            for (int ni = 0; ni < 2; ++ni) {
                const int n = br0 + 16*ni + l15;
                short8 sH = *(const short8*)&SBh[n][ko];
                short8 sL = *(const short8*)&SBl[n][ko];
                short8 vH = *(const short8*)&VBh[n][ko];
                short8 vL = *(const short8*)&VBl[n][ko];
                accS[0][ni] = mfma_bf16(aH0, sH, accS[0][ni]);
                accS[0][ni] = mfma_bf16(aH0, sL, accS[0][ni]);
                accS[0][ni] = mfma_bf16(aL0, sH, accS[0][ni]);
                accS[1][ni] = mfma_bf16(aH1, sH, accS[1][ni]);
                accS[1][ni] = mfma_bf16(aH1, sL, accS[1][ni]);
                accS[1][ni] = mfma_bf16(aL1, sH, accS[1][ni]);
                accV[0][ni] = mfma_bf16(aH0, vH, accV[0][ni]);
                accV[0][ni] = mfma_bf16(aH0, vL, accV[0][ni]);
                accV[0][ni] = mfma_bf16(aL0, vH, accV[0][ni]);
                accV[1][ni] = mfma_bf16(aH1, vH, accV[1][ni]);
                accV[1][ni] = mfma_bf16(aH1, vL, accV[1][ni]);
                accV[1][ni] = mfma_bf16(aL1, vH, accV[1][ni]);
            }
        }
        __syncthreads();   // all state reads done

        if (s + 1 < CH) {
#pragma unroll
            for (int mi = 0; mi < 2; ++mi)
#pragma unroll
            for (int ni = 0; ni < 2; ++ni) {
                const int cc = br0 + 16*ni + l15, r0 = mr0 + 16*mi + 4*quad;
                short4v h4, l4;
#pragma unroll
                for (int r = 0; r < 4; ++r) { short hh,ll; split_bf16(accS[mi][ni][r],hh,ll); h4[r]=hh; l4[r]=ll; }
                *(short4v*)&SBh[cc][r0] = h4; *(short4v*)&SBl[cc][r0] = l4;
#pragma unroll
                for (int r = 0; r < 4; ++r) { short hh,ll; split_bf16(accV[mi][ni][r],hh,ll); h4[r]=hh; l4[r]=ll; }
                *(short4v*)&VBh[cc][r0] = h4; *(short4v*)&VBl[cc][r0] = l4;
            }
        }
    }

    unsigned* po = P32 + (size_t)c * 4096;
#pragma unroll
    for (int mi = 0; mi < 2; ++mi)
#pragma unroll
    for (int ni = 0; ni < 2; ++ni) {
        const int cc = br0 + 16*ni + l15, r0 = mr0 + 16*mi + 4*quad;
        *(floatx4*)(VT + (size_t)c*4096 + cc*64 + r0) = accV[mi][ni];
#pragma unroll
        for (int r = 0; r < 4; ++r) {
            short hh, ll; split_bf16(accS[mi][ni][r], hh, ll);
            po[(r0 + r)*64 + cc] = ((unsigned)(unsigned short)hh << 16) | (unsigned)(unsigned short)ll;
        }
    }
}

// ---------------------------------------------------------------------------
// Sequential in-place scan of 8 elements per block.
// idx = blockIdx.x*bstride + off0 + i*estride.  Slot i <- prefix 0..i.
// Pnew = P_i*Pacc (Aop = P_i), Vnew = P_i*Vacc + V_i.
// ---------------------------------------------------------------------------
__global__ __launch_bounds__(256, 2)
void hippo_seqscan(unsigned* __restrict__ P32, float* __restrict__ VT,
                   int bstride, int off0, int estride)
{
    __shared__ short PAh[NB][AS], PAl[NB][AS];
    __shared__ short PBh[NB][AS], PBl[NB][AS];
    __shared__ short VBh[NB][AS], VBl[NB][AS];

    const int tid = threadIdx.x;
    const int base = blockIdx.x * bstride + off0;
    const int w = tid >> 6, lane = tid & 63;
    const int quad = lane >> 4, l15 = lane & 15;
    const int wm = w >> 1, wb = w & 1;
    const int mr0 = 32*wm, br0 = 32*wb;

    // element 0 -> Bop LDS. P packed row-major -> scatter-transpose (once).
    {
        const unsigned* p0 = P32 + (size_t)base * 4096;
        const float*    v0 = VT  + (size_t)base * 4096;
#pragma unroll
        for (int q = 0; q < 4; ++q) {
            int f = tid + q * 256;
            int k = f & 63, m0 = (f >> 6) * 4;
            uint4v pk = *(const uint4v*)(p0 + k * 64 + m0);
#pragma unroll
            for (int r = 0; r < 4; ++r) {
                PBh[m0 + r][k] = (short)(pk[r] >> 16);
                PBl[m0 + r][k] = (short)(pk[r] & 0xFFFFu);
            }
        }
#pragma unroll
        for (int q = 0; q < 4; ++q) {
            int f = tid + q * 256;
            int n = f >> 4, k0 = (f & 15) * 4;
            float4 vv = *(const float4*)(v0 + n * 64 + k0);
            float va[4] = {vv.x, vv.y, vv.z, vv.w};
            short4v vh4, vl4;
#pragma unroll
            for (int r = 0; r < 4; ++r) { short hh, ll; split_bf16(va[r], hh, ll); vh4[r]=hh; vl4[r]=ll; }
            *(short4v*)&VBh[n][k0] = vh4; *(short4v*)&VBl[n][k0] = vl4;
        }
    }

    uint4v preA[4]; float4 preV[2][2];
    {
        const unsigned* pc = P32 + (size_t)(base + estride) * 4096;
        const float*    vc = VT  + (size_t)(base + estride) * 4096;
#pragma unroll
        for (int q = 0; q < 4; ++q) {
            int f = tid + q * 256;
            int m = f >> 4, k0 = (f & 15) * 4;
            preA[q] = *(const uint4v*)(pc + m * 64 + k0);
        }
#pragma unroll
        for (int mi = 0; mi < 2; ++mi)
#pragma unroll
        for (int ni = 0; ni < 2; ++ni) {
            const int cc = br0 + 16*ni + l15, r0 = mr0 + 16*mi + 4*quad;
            preV[mi][ni] = *(const float4*)(vc + cc * 64 + r0);
        }
    }

    for (int i = 1; i < 8; ++i) {
        // stage Aop = P_i: unpack packed pairs, contiguous b64 writes
#pragma unroll
        for (int q = 0; q < 4; ++q) {
            int f = tid + q * 256;
            int m = f >> 4, k0 = (f & 15) * 4;
            short4v h4, l4;
#pragma unroll
            for (int r = 0; r < 4; ++r) { h4[r] = (short)(preA[q][r] >> 16); l4[r] = (short)(preA[q][r] & 0xFFFFu); }
            *(short4v*)&PAh[m][k0] = h4;
            *(short4v*)&PAl[m][k0] = l4;
        }
        floatx4 accP[2][2], accV[2][2];
#pragma unroll
        for (int mi = 0; mi < 2; ++mi)
#pragma unroll
        for (int ni = 0; ni < 2; ++ni) {
            accV[mi][ni][0] = preV[mi][ni].x; accV[mi][ni][1] = preV[mi][ni].y;
            accV[mi][ni][2] = preV[mi][ni].z; accV[mi][ni][3] = preV[mi][ni].w;
            accP[mi][ni][0]=accP[mi][ni][1]=accP[mi][ni][2]=accP[mi][ni][3]=0.0f;
        }
        if (i + 1 < 8) {
            const unsigned* pc = P32 + (size_t)(base + (i + 1) * estride) * 4096;
            const float*    vc = VT  + (size_t)(base + (i + 1) * estride) * 4096;
#pragma unroll
            for (int q = 0; q < 4; ++q) {
                int f = tid + q * 256;
                int m = f >> 4, k0 = (f & 15) * 4;
                preA[q] = *(const uint4v*)(pc + m * 64 + k0);
            }
#pragma unroll
            for (int mi = 0; mi < 2; ++mi)
#pragma unroll
            for (int ni = 0; ni < 2; ++ni) {
                const int cc = br0 + 16*ni + l15, r0 = mr0 + 16*mi + 4*quad;
                preV[mi][ni] = *(const float4*)(vc + cc * 64 + r0);
            }
        }
        __syncthreads();

#pragma unroll
        for (int kc = 0; kc < 2; ++kc) {
            const int ko = 32*kc + 8*quad;
            short8 aH0 = *(const short8*)&PAh[mr0 + l15][ko];
            short8 aL0 = *(const short8*)&PAl[mr0 + l15][ko];
            short8 aH1 = *(const short8*)&PAh[mr0 + 16 + l15][ko];
            short8 aL1 = *(const short8*)&PAl[mr0 + 16 + l15][ko];
#pragma unroll
            for (int ni = 0; ni < 2; ++ni) {
                const int n = br0 + 16*ni + l15;
                short8 pH = *(const short8*)&PBh[n][ko];
                short8 pL = *(const short8*)&PBl[n][ko];
                short8 vH = *(const short8*)&VBh[n][ko];
                short8 vL = *(const short8*)&VBl[n][ko];
                accP[0][ni] = mfma_bf16(aH0, pH, accP[0][ni]);
                accP[0][ni] = mfma_bf16(aH0, pL, accP[0][ni]);
                accP[0][ni] = mfma_bf16(aL0, pH, accP[0][ni]);
                accP[1][ni] = mfma_bf16(aH1, pH, accP[1][ni]);
                accP[1][ni] = mfma_bf16(aH1, pL, accP[1][ni]);
                accP[1][ni] = mfma_bf16(aL1, pH, accP[1][ni]);
                accV[0][ni] = mfma_bf16(aH0, vH, accV[0][ni]);
                accV[0][ni] = mfma_bf16(aH0, vL, accV[0][ni]);
                accV[0][ni] = mfma_bf16(aL0, vH, accV[0][ni]);
                accV[1][ni] = mfma_bf16(aH1, vH, accV[1][ni]);
                accV[1][ni] = mfma_bf16(aH1, vL, accV[1][ni]);
                accV[1][ni] = mfma_bf16(aL1, vH, accV[1][ni]);
            }
        }
        __syncthreads();

        const int idx = base + i * estride;
        unsigned* po = P32 + (size_t)idx * 4096;
#pragma unroll
        for (int mi = 0; mi < 2; ++mi)
#pragma unroll
        for (int ni = 0; ni < 2; ++ni) {
            const int cc = br0 + 16*ni + l15, r0 = mr0 + 16*mi + 4*quad;
            *(floatx4*)(VT + (size_t)idx * 4096 + cc * 64 + r0) = accV[mi][ni];
            short4v h4, l4;
#pragma unroll
            for (int r = 0; r < 4; ++r) {
                short hh, ll; split_bf16(accP[mi][ni][r], hh, ll);
                po[(r0 + r) * 64 + cc] = ((unsigned)(unsigned short)hh << 16) | (unsigned)(unsigned short)ll;
                h4[r] = hh; l4[r] = ll;
            }
            *(short4v*)&PBh[cc][r0] = h4; *(short4v*)&PBl[cc][r0] = l4;
#pragma unroll
            for (int r = 0; r < 4; ++r) { short hh,ll; split_bf16(accV[mi][ni][r],hh,ll); h4[r]=hh; l4[r]=ll; }
            *(short4v*)&VBh[cc][r0] = h4; *(short4v*)&VBl[cc][r0] = l4;
        }
    }
}

// ---------------------------------------------------------------------------
// S3: 1 block. E_0 = 0; E_{s+1} = P[64s+63]*E_s + V[64s+63].
// Stores E_{s+1} fp32 into dead P32 slot idx=64s+63, layout [b][n].
// ---------------------------------------------------------------------------
__global__ __launch_bounds__(256, 2)
void hippo_s3(unsigned* __restrict__ P32, const float* __restrict__ VT)
{
    __shared__ short PAh[NB][AS], PAl[NB][AS];
    __shared__ short EBh[NB][AS], EBl[NB][AS];
    const int tid = threadIdx.x;
    const int w = tid >> 6, lane = tid & 63, quad = lane >> 4, l15 = lane & 15;
    const int wm = w >> 1, wb = w & 1;
    const int mr0 = 32*wm, br0 = 32*wb;

#pragma unroll
    for (int q = 0; q < 16; ++q) {
        int f = tid + q * 256; EBh[f >> 6][f & 63] = 0; EBl[f >> 6][f & 63] = 0;
    }
    for (int s = 0; s < 7; ++s) {
        const int idx = 64 * s + 63;
        const unsigned* pc = P32 + (size_t)idx * 4096;
        const float*    vc = VT  + (size_t)idx * 4096;
#pragma unroll
        for (int q = 0; q < 4; ++q) {
            int f = tid + q * 256;
            int m = f >> 4, k0 = (f & 15) * 4;
            uint4v pk = *(const uint4v*)(pc + m * 64 + k0);
            short4v h4, l4;
#pragma unroll
            for (int r = 0; r < 4; ++r) { h4[r] = (short)(pk[r] >> 16); l4[r] = (short)(pk[r] & 0xFFFFu); }
            *(short4v*)&PAh[m][k0] = h4;
            *(short4v*)&PAl[m][k0] = l4;
        }
        floatx4 acc[2][2];
#pragma unroll
        for (int mi = 0; mi < 2; ++mi)
#pragma unroll
        for (int ni = 0; ni < 2; ++ni) {
            const int cc = br0 + 16*ni + l15, r0 = mr0 + 16*mi + 4*quad;
            float4 vv = *(const float4*)(vc + cc * 64 + r0);
            acc[mi][ni][0]=vv.x; acc[mi][ni][1]=vv.y; acc[mi][ni][2]=vv.z; acc[mi][ni][3]=vv.w;
        }
        __syncthreads();
#pragma unroll
        for (int kc = 0; kc < 2; ++kc) {
            const int ko = 32*kc + 8*quad;
            short8 aH0 = *(const short8*)&PAh[mr0 + l15][ko];
            short8 aL0 = *(const short8*)&PAl[mr0 + l15][ko];
            short8 aH1 = *(const short8*)&PAh[mr0 + 16 + l15][ko];
            short8 aL1 = *(const short8*)&PAl[mr0 + 16 + l15][ko];
#pragma unroll
            for (int ni = 0; ni < 2; ++ni) {
                const int n = br0 + 16*ni + l15;
                short8 eH = *(const short8*)&EBh[n][ko];
                short8 eL = *(const short8*)&EBl[n][ko];
                acc[0][ni] = mfma_bf16(aH0, eH, acc[0][ni]);
                acc[0][ni] = mfma_bf16(aH0, eL, acc[0][ni]);
                acc[0][ni] = mfma_bf16(aL0, eH, acc[0][ni]);
                acc[1][ni] = mfma_bf16(aH1, eH, acc[1][ni]);
                acc[1][ni] = mfma_bf16(aH1, eL, acc[1][ni]);
                acc[1][ni] = mfma_bf16(aL1, eH, acc[1][ni]);
            }
        }
        __syncthreads();
        float* eo = (float*)(P32 + (size_t)idx * 4096);
#pragma unroll
        for (int mi = 0; mi < 2; ++mi)
#pragma unroll
        for (int ni = 0; ni < 2; ++ni) {
            const int cc = br0 + 16*ni + l15, r0 = mr0 + 16*mi + 4*quad;
            *(floatx4*)(eo + cc * 64 + r0) = acc[mi][ni];
            short4v h4, l4;
#pragma unroll
            for (int r = 0; r < 4; ++r) { short hh,ll; split_bf16(acc[mi][ni][r],hh,ll); h4[r]=hh; l4[r]=ll; }
            *(short4v*)&EBh[cc][r0] = h4; *(short4v*)&EBl[cc][r0] = l4;
        }
    }
}

// ---------------------------------------------------------------------------
// Phase 3: entering state = (super E) combined with stored prefixes, then
// x <- A[t] x + u_t for the 8 local steps; out[t][b][n] from C-layout regs.
// ---------------------------------------------------------------------------
__global__ __launch_bounds__(256, 2)
void hippo_phase3(const float* __restrict__ inp, const float* __restrict__ Ag,
                  const float* __restrict__ Bst, const unsigned* __restrict__ P32,
                  const float* __restrict__ VT, float* __restrict__ out)
{
    __shared__ short Ah[NB][AS], Al[NB][AS];
    __shared__ short XBh[NB][AS], XBl[NB][AS];

    const int tid = threadIdx.x, c = blockIdx.x, t0 = c * CH;
    const int w = tid >> 6, lane = tid & 63, quad = lane >> 4, l15 = lane & 15;
    const int wm = w >> 1, wb = w & 1;
    const int mr0 = 32*wm, br0 = 32*wb;
    const int sup = c >> 6, g = c >> 3, gi = g & 7, j = c & 7;

    // A[t0] prefetch issued early (hides HBM under prefix combines)
    float4 pre[4];
    {
        const float4* Ap = (const float4*)(Ag + (size_t)t0 * 4096);
#pragma unroll
        for (int q = 0; q < 4; ++q) pre[q] = Ap[tid + q * 256];
    }

    // ---- entering super state ----
    if (sup == 0) {
#pragma unroll
        for (int q = 0; q < 16; ++q) { int f = tid + q*256; XBh[f>>6][f&63] = 0; XBl[f>>6][f&63] = 0; }
    } else {
        const float* e = (const float*)(P32 + (size_t)(64*(sup-1) + 63) * 4096);  // E_sup [b][n]
#pragma unroll
        for (int q = 0; q < 4; ++q) {
            int f = tid + q*256; int b = f>>4, k0 = (f&15)*4;
            float4 v = *(const float4*)(e + b*64 + k0);
            float va[4] = {v.x,v.y,v.z,v.w};
            short4v h4, l4;
#pragma unroll
            for (int r=0;r<4;++r){short hh,ll;split_bf16(va[r],hh,ll);h4[r]=hh;l4[r]=ll;}
            *(short4v*)&XBh[b][k0] = h4; *(short4v*)&XBl[b][k0] = l4;
        }
    }

    // ---- apply stored prefixes: X <- P[idx]*X + V[idx] ----
    auto combine = [&](int idx) {
        const unsigned* pc = P32 + (size_t)idx * 4096;
        const float*    vc = VT  + (size_t)idx * 4096;
#pragma unroll
        for (int q = 0; q < 4; ++q) {
            int f = tid + q*256;
            int m = f >> 4, k0 = (f & 15) * 4;
            uint4v pk = *(const uint4v*)(pc + m * 64 + k0);
            short4v h4, l4;
#pragma unroll
            for (int r = 0; r < 4; ++r) { h4[r] = (short)(pk[r] >> 16); l4[r] = (short)(pk[r] & 0xFFFFu); }
            *(short4v*)&Ah[m][k0] = h4;
            *(short4v*)&Al[m][k0] = l4;
        }
        floatx4 acc[2][2];
#pragma unroll
        for (int mi = 0; mi < 2; ++mi)
#pragma unroll
        for (int ni = 0; ni < 2; ++ni) {
            const int cc = br0 + 16*ni + l15, r0 = mr0 + 16*mi + 4*quad;
            float4 vv = *(const float4*)(vc + cc*64 + r0);
            acc[mi][ni][0]=vv.x; acc[mi][ni][1]=vv.y; acc[mi][ni][2]=vv.z; acc[mi][ni][3]=vv.w;
        }
        __syncthreads();
#pragma unroll
        for (int kc = 0; kc < 2; ++kc) {
            const int ko = 32*kc + 8*quad;
            short8 aH0 = *(const short8*)&Ah[mr0 + l15][ko];
            short8 aL0 = *(const short8*)&Al[mr0 + l15][ko];
            short8 aH1 = *(const short8*)&Ah[mr0 + 16 + l15][ko];
            short8 aL1 = *(const short8*)&Al[mr0 + 16 + l15][ko];
#pragma unroll
            for (int ni = 0; ni < 2; ++ni) {
                const int n = br0 + 16*ni + l15;
                short8 xH = *(const short8*)&XBh[n][ko];
                short8 xL = *(const short8*)&XBl[n][ko];
                acc[0][ni] = mfma_bf16(aH0, xH, acc[0][ni]);
                acc[0][ni] = mfma_bf16(aH0, xL, acc[0][ni]);
                acc[0][ni] = mfma_bf16(aL0, xH, acc[0][ni]);
                acc[1][ni] = mfma_bf16(aH1, xH, acc[1][ni]);
                acc[1][ni] = mfma_bf16(aH1, xL, acc[1][ni]);
                acc[1][ni] = mfma_bf16(aL1, xH, acc[1][ni]);
            }
        }
        __syncthreads();
#pragma unroll
        for (int mi = 0; mi < 2; ++mi)
#pragma unroll
        for (int ni = 0; ni < 2; ++ni) {
            const int cc = br0 + 16*ni + l15, r0 = mr0 + 16*mi + 4*quad;
            short4v h4, l4;
#pragma unroll
            for (int r=0;r<4;++r){short hh,ll;split_bf16(acc[mi][ni][r],hh,ll);h4[r]=hh;l4[r]=ll;}
            *(short4v*)&XBh[cc][r0] = h4; *(short4v*)&XBl[cc][r0] = l4;
        }
    };
    if (gi) combine(8*g - 1);   // in-super group prefix (S2 output)
    if (j)  combine(c - 1);     // in-group chunk prefix (S1 output)

    // b/i prefetch for t0
    float preB[2][4], preI[2];
#pragma unroll
    for (int mi = 0; mi < 2; ++mi)
#pragma unroll
        for (int r = 0; r < 4; ++r)
            preB[mi][r] = Bst[(size_t)t0*64 + mr0 + 16*mi + 4*quad + r];
    preI[0] = inp[(size_t)t0*64 + br0 + l15];
    preI[1] = inp[(size_t)t0*64 + br0 + 16 + l15];

    // ---- 8 local time steps ----
    floatx4 acc[2][2];
    for (int s = 0; s < CH; ++s) {
        const int t = t0 + s;
#pragma unroll
        for (int q = 0; q < 4; ++q) {
            int f = tid + q*256; int m = f>>4, k0 = (f&15)*4;
            float vv[4] = {pre[q].x,pre[q].y,pre[q].z,pre[q].w};
            short4v h4, l4;
#pragma unroll
            for (int r=0;r<4;++r){short hh,ll;split_bf16(vv[r],hh,ll);h4[r]=hh;l4[r]=ll;}
            *(short4v*)&Ah[m][k0] = h4; *(short4v*)&Al[m][k0] = l4;
        }
        float bcur[2][4], icur[2];
#pragma unroll
        for (int mi=0;mi<2;++mi)
#pragma unroll
            for (int r=0;r<4;++r) bcur[mi][r] = preB[mi][r];
        icur[0]=preI[0]; icur[1]=preI[1];
        if (s + 1 < CH) {
            const int t1 = t + 1;
            const float4* Ap = (const float4*)(Ag + (size_t)t1 * 4096);
#pragma unroll
            for (int q = 0; q < 4; ++q) pre[q] = Ap[tid + q * 256];
#pragma unroll
            for (int mi=0;mi<2;++mi)
#pragma unroll
                for (int r=0;r<4;++r)
                    preB[mi][r] = Bst[(size_t)t1*64 + mr0 + 16*mi + 4*quad + r];
            preI[0] = inp[(size_t)t1*64 + br0 + l15];
            preI[1] = inp[(size_t)t1*64 + br0 + 16 + l15];
        }
        __syncthreads();

#pragma unroll
        for (int mi=0;mi<2;++mi)
#pragma unroll
        for (int ni=0;ni<2;++ni)
#pragma unroll
        for (int r=0;r<4;++r) acc[mi][ni][r] = bcur[mi][r] * icur[ni];
#pragma unroll
        for (int kc = 0; kc < 2; ++kc) {
            const int ko = 32*kc + 8*quad;
            short8 aH0 = *(const short8*)&Ah[mr0 + l15][ko];
            short8 aL0 = *(const short8*)&Al[mr0 + l15][ko];
            short8 aH1 = *(const short8*)&Ah[mr0 + 16 + l15][ko];
            short8 aL1 = *(const short8*)&Al[mr0 + 16 + l15][ko];
#pragma unroll
            for (int ni = 0; ni < 2; ++ni) {
                const int n = br0 + 16*ni + l15;
                short8 xH = *(const short8*)&XBh[n][ko];
                short8 xL = *(const short8*)&XBl[n][ko];
                acc[0][ni] = mfma_bf16(aH0, xH, acc[0][ni]);
                acc[0][ni] = mfma_bf16(aH0, xL, acc[0][ni]);
                acc[0][ni] = mfma_bf16(aL0, xH, acc[0][ni]);
                acc[1][ni] = mfma_bf16(aH1, xH, acc[1][ni]);
                acc[1][ni] = mfma_bf16(aH1, xL, acc[1][ni]);
                acc[1][ni] = mfma_bf16(aL1, xH, acc[1][ni]);
            }
        }
        __syncthreads();
#pragma unroll
        for (int mi = 0; mi < 2; ++mi)
#pragma unroll
        for (int ni = 0; ni < 2; ++ni) {
            const int cc = br0 + 16*ni + l15, r0 = mr0 + 16*mi + 4*quad;
            *(floatx4*)(out + (size_t)t*4096 + cc*64 + r0) = acc[mi][ni];   // out[t][b][n0..3]
            if (s + 1 < CH) {
                short4v h4, l4;
#pragma unroll
                for (int r=0;r<4;++r){short hh,ll;split_bf16(acc[mi][ni][r],hh,ll);h4[r]=hh;l4[r]=ll;}
                *(short4v*)&XBh[cc][r0] = h4; *(short4v*)&XBl[cc][r0] = l4;
            }
        }
    }
}

extern "C" void kernel_launch(void* const* d_in, const int* in_sizes, int n_in,
                              void* d_out, int out_size, void* d_ws, size_t ws_size,
                              hipStream_t stream)
{
    const float* inp = (const float*)d_in[0];   // (L, B)
    const float* A   = (const float*)d_in[1];   // (L, N, N)
    const float* Bst = (const float*)d_in[2];   // (L, N)
    float* out = (float*)d_out;                  // (L, B, N)
    float* ws  = (float*)d_ws;                   // 16 MB used

    unsigned* P32 = (unsigned*)ws;               // 8 MB: packed hi|lo, row-major
    float*    VT  = ws + (size_t)CN * 4096;      // 8 MB: fp32, transposed

    hippo_phase1<<<CN, 256, 0, stream>>>(inp, A, Bst, P32, VT);
    hippo_seqscan<<<64, 256, 0, stream>>>(P32, VT, 8, 0, 1);
    hippo_seqscan<<<8, 256, 0, stream>>>(P32, VT, 64, 7, 8);
    hippo_s3<<<1, 256, 0, stream>>>(P32, VT);
    hippo_phase3<<<CN, 256, 0, stream>>>(inp, A, Bst, P32, VT, out);
}